// Round 3
// baseline (792.165 us; speedup 1.0000x reference)
//
#include <hip/hip_runtime.h>

#define N_NODES 100000
#define N_EDGES 1600000

__device__ __forceinline__ float rlane(float v, int l) {
  return __uint_as_float(__builtin_amdgcn_readlane(__float_as_uint(v), l));
}
__device__ __forceinline__ unsigned short f2bf(float f) {  // RNE, normal inputs
  unsigned u = __float_as_uint(f);
  return (unsigned short)((u + 0x7fffu + ((u >> 16) & 1u)) >> 16);
}
__device__ __forceinline__ float bf2f(unsigned short b) {
  return __uint_as_float(((unsigned)b) << 16);
}

// ---- CSR build -------------------------------------------------------------

__global__ void k_hist(const int* __restrict__ dst, int* __restrict__ deg) {
  int stride = gridDim.x * blockDim.x;
  for (int e = blockIdx.x * blockDim.x + threadIdx.x; e < N_EDGES; e += stride)
    atomicAdd(&deg[dst[e]], 1);
}

__global__ void k_blocksum(const int* __restrict__ deg, int* __restrict__ bsum) {
  int i = blockIdx.x * 256 + threadIdx.x;
  int v = (i < N_NODES) ? deg[i] : 0;
  #pragma unroll
  for (int d = 32; d; d >>= 1) v += __shfl_down(v, d);
  __shared__ int wsum[4];
  if ((threadIdx.x & 63) == 0) wsum[threadIdx.x >> 6] = v;
  __syncthreads();
  if (threadIdx.x == 0) bsum[blockIdx.x] = wsum[0] + wsum[1] + wsum[2] + wsum[3];
}

__global__ void k_scan_bsum(int* __restrict__ bsum, int nb, int* __restrict__ off) {
  int lane = threadIdx.x;
  int running = 0;
  for (int base = 0; base < nb; base += 64) {
    int i = base + lane;
    int v = (i < nb) ? bsum[i] : 0;
    int inc = v;
    #pragma unroll
    for (int d = 1; d < 64; d <<= 1) { int y = __shfl_up(inc, d); if (lane >= d) inc += y; }
    if (i < nb) bsum[i] = running + inc - v;
    running += __shfl(inc, 63);
  }
  if (lane == 0) off[N_NODES] = running;
}

__global__ void k_offsets(const int* __restrict__ deg, const int* __restrict__ bsum,
                          int* __restrict__ off, int* __restrict__ cur) {
  int i = blockIdx.x * 256 + threadIdx.x;
  int lane = threadIdx.x & 63, w = threadIdx.x >> 6;
  int v = (i < N_NODES) ? deg[i] : 0;
  int inc = v;
  #pragma unroll
  for (int d = 1; d < 64; d <<= 1) { int y = __shfl_up(inc, d); if (lane >= d) inc += y; }
  __shared__ int wtot[4];
  if (lane == 63) wtot[w] = inc;
  __syncthreads();
  int base = bsum[blockIdx.x];
  for (int j = 0; j < w; j++) base += wtot[j];
  if (i < N_NODES) {
    int ex = base + inc - v;
    off[i] = ex;
    cur[i] = ex;
  }
}

__global__ void k_fill(const int* __restrict__ src, const int* __restrict__ dst,
                       int* __restrict__ cur, int* __restrict__ esrc) {
  int stride = gridDim.x * blockDim.x;
  for (int e = blockIdx.x * blockDim.x + threadIdx.x; e < N_EDGES; e += stride) {
    int d = dst[e];
    int p = atomicAdd(&cur[d], 1);
    esrc[p] = src[e];
  }
}

// ---- f32 -> bf16 table conversion ------------------------------------------

__global__ void k_cvt(const float* __restrict__ in, unsigned short* __restrict__ outb) {
  int i = blockIdx.x * blockDim.x + threadIdx.x;  // one float4 per thread
  const int n4 = (N_NODES * 64) / 4;
  if (i < n4) {
    float4 v = ((const float4*)in)[i];
    ushort4 u;
    u.x = f2bf(v.x); u.y = f2bf(v.y); u.z = f2bf(v.z); u.w = f2bf(v.w);
    ((ushort4*)outb)[i] = u;
  }
}

// ---- fused SAGE layer: one wave per node, lane = feature -------------------
// featb: bf16 [N,64] input table (self + neighbors). Output: bf16 table and/or f32.

template <bool RELU, bool OUT_BF>
__global__ void k_layer(const unsigned short* __restrict__ featb,
                        const int* __restrict__ off, const int* __restrict__ esrc,
                        const float* __restrict__ Ws, const float* __restrict__ Wn,
                        const float* __restrict__ bias,
                        float* __restrict__ outf, unsigned short* __restrict__ outb) {
  const int lane = threadIdx.x & 63;
  const int wib  = threadIdx.x >> 6;
  const int wpb  = blockDim.x >> 6;
  const int wid  = blockIdx.x * wpb + wib;
  const int nw   = gridDim.x * wpb;

  float wS[64], wN[64];
  #pragma unroll
  for (int k = 0; k < 64; k++) {
    wS[k] = Ws[k * 64 + lane];
    wN[k] = Wn[k * 64 + lane];
  }
  const float bv = bias[lane];

  for (int n = wid; n < N_NODES; n += nw) {
    const int o0 = off[n], o1 = off[n + 1];
    float acc = 0.f;
    int i = o0;
    for (; i + 8 <= o1; i += 8) {
      int s0 = __builtin_amdgcn_readfirstlane(esrc[i]);
      int s1 = __builtin_amdgcn_readfirstlane(esrc[i + 1]);
      int s2 = __builtin_amdgcn_readfirstlane(esrc[i + 2]);
      int s3 = __builtin_amdgcn_readfirstlane(esrc[i + 3]);
      int s4 = __builtin_amdgcn_readfirstlane(esrc[i + 4]);
      int s5 = __builtin_amdgcn_readfirstlane(esrc[i + 5]);
      int s6 = __builtin_amdgcn_readfirstlane(esrc[i + 6]);
      int s7 = __builtin_amdgcn_readfirstlane(esrc[i + 7]);
      float a0 = bf2f(featb[s0 * 64 + lane]);
      float a1 = bf2f(featb[s1 * 64 + lane]);
      float a2 = bf2f(featb[s2 * 64 + lane]);
      float a3 = bf2f(featb[s3 * 64 + lane]);
      float a4 = bf2f(featb[s4 * 64 + lane]);
      float a5 = bf2f(featb[s5 * 64 + lane]);
      float a6 = bf2f(featb[s6 * 64 + lane]);
      float a7 = bf2f(featb[s7 * 64 + lane]);
      acc += ((a0 + a1) + (a2 + a3)) + ((a4 + a5) + (a6 + a7));
    }
    for (; i < o1; ++i) acc += bf2f(featb[__builtin_amdgcn_readfirstlane(esrc[i]) * 64 + lane]);
    const int dg = o1 - o0;
    acc = (dg > 0) ? acc * (1.0f / (float)dg) : 0.f;

    const float sv = bf2f(featb[n * 64 + lane]);
    float p0 = bv, p1 = 0.f, p2 = 0.f, p3 = 0.f;
    #pragma unroll
    for (int k = 0; k < 64; k += 2) {
      p0 += rlane(sv,  k)     * wS[k];
      p1 += rlane(acc, k)     * wN[k];
      p2 += rlane(sv,  k + 1) * wS[k + 1];
      p3 += rlane(acc, k + 1) * wN[k + 1];
    }
    float o = (p0 + p1) + (p2 + p3);
    if (RELU) o = fmaxf(o, 0.f);
    if (OUT_BF) outb[n * 64 + lane] = f2bf(o);
    else        outf[n * 64 + lane] = o;
  }
}

// ---- launch ----------------------------------------------------------------

extern "C" void kernel_launch(void* const* d_in, const int* in_sizes, int n_in,
                              void* d_out, int out_size, void* d_ws, size_t ws_size,
                              hipStream_t stream) {
  const float* x   = (const float*)d_in[0];
  const int*   src = (const int*)d_in[1];
  const int*   dst = (const int*)d_in[2];
  const float* Ws1 = (const float*)d_in[3];
  const float* Wn1 = (const float*)d_in[4];
  const float* b1  = (const float*)d_in[5];
  const float* Ws2 = (const float*)d_in[6];
  const float* Wn2 = (const float*)d_in[7];
  const float* b2  = (const float*)d_in[8];
  float* out = (float*)d_out;

  char* ws = (char*)d_ws;
  int*            deg  = (int*)(ws + 0);          // N ints
  int*            off  = (int*)(ws + 400128);     // N+1 ints
  int*            cur  = (int*)(ws + 800512);     // N ints
  int*            bsum = (int*)(ws + 1200640);    // ~400 ints
  int*            esrc = (int*)(ws + 1202688);    // E ints
  unsigned short* xbf  = (unsigned short*)(ws + 7602688);   // N*64 bf16
  unsigned short* hbf  = (unsigned short*)(ws + 20402688);  // N*64 bf16 (ends ~33.2MB)

  const int NB = (N_NODES + 255) / 256; // 391

  hipMemsetAsync(deg, 0, N_NODES * sizeof(int), stream);
  k_hist<<<4096, 256, 0, stream>>>(dst, deg);
  k_blocksum<<<NB, 256, 0, stream>>>(deg, bsum);
  k_scan_bsum<<<1, 64, 0, stream>>>(bsum, NB, off);
  k_offsets<<<NB, 256, 0, stream>>>(deg, bsum, off, cur);
  k_fill<<<4096, 256, 0, stream>>>(src, dst, cur, esrc);
  k_cvt<<<(N_NODES * 16 + 255) / 256, 256, 0, stream>>>(x, xbf);
  k_layer<true,  true ><<<4096, 256, 0, stream>>>(xbf, off, esrc, Ws1, Wn1, b1, nullptr, hbf);
  k_layer<false, false><<<4096, 256, 0, stream>>>(hbf, off, esrc, Ws2, Wn2, b2, out, nullptr);
}

// Round 4
// 392.094 us; speedup vs baseline: 2.0203x; 2.0203x over previous
//
#include <hip/hip_runtime.h>

#define N_NODES 100000
#define N_EDGES 1600000

typedef __attribute__((ext_vector_type(8))) short short8;
typedef __attribute__((ext_vector_type(4))) float float4v;

__device__ __forceinline__ unsigned short f2bf(float f) {  // RNE
  unsigned u = __float_as_uint(f);
  return (unsigned short)((u + 0x7fffu + ((u >> 16) & 1u)) >> 16);
}
__device__ __forceinline__ float bflo(unsigned d) { return __uint_as_float(d << 16); }
__device__ __forceinline__ float bfhi(unsigned d) { return __uint_as_float(d & 0xffff0000u); }

// ---- CSR build (unchanged from passing R2) ---------------------------------

__global__ void k_hist(const int* __restrict__ dst, int* __restrict__ deg) {
  int stride = gridDim.x * blockDim.x;
  for (int e = blockIdx.x * blockDim.x + threadIdx.x; e < N_EDGES; e += stride)
    atomicAdd(&deg[dst[e]], 1);
}

__global__ void k_blocksum(const int* __restrict__ deg, int* __restrict__ bsum) {
  int i = blockIdx.x * 256 + threadIdx.x;
  int v = (i < N_NODES) ? deg[i] : 0;
  #pragma unroll
  for (int d = 32; d; d >>= 1) v += __shfl_down(v, d);
  __shared__ int wsum[4];
  if ((threadIdx.x & 63) == 0) wsum[threadIdx.x >> 6] = v;
  __syncthreads();
  if (threadIdx.x == 0) bsum[blockIdx.x] = wsum[0] + wsum[1] + wsum[2] + wsum[3];
}

__global__ void k_scan_bsum(int* __restrict__ bsum, int nb, int* __restrict__ off) {
  int lane = threadIdx.x;
  int running = 0;
  for (int base = 0; base < nb; base += 64) {
    int i = base + lane;
    int v = (i < nb) ? bsum[i] : 0;
    int inc = v;
    #pragma unroll
    for (int d = 1; d < 64; d <<= 1) { int y = __shfl_up(inc, d); if (lane >= d) inc += y; }
    if (i < nb) bsum[i] = running + inc - v;
    running += __shfl(inc, 63);
  }
  if (lane == 0) off[N_NODES] = running;
}

__global__ void k_offsets(const int* __restrict__ deg, const int* __restrict__ bsum,
                          int* __restrict__ off, int* __restrict__ cur) {
  int i = blockIdx.x * 256 + threadIdx.x;
  int lane = threadIdx.x & 63, w = threadIdx.x >> 6;
  int v = (i < N_NODES) ? deg[i] : 0;
  int inc = v;
  #pragma unroll
  for (int d = 1; d < 64; d <<= 1) { int y = __shfl_up(inc, d); if (lane >= d) inc += y; }
  __shared__ int wtot[4];
  if (lane == 63) wtot[w] = inc;
  __syncthreads();
  int base = bsum[blockIdx.x];
  for (int j = 0; j < w; j++) base += wtot[j];
  if (i < N_NODES) {
    int ex = base + inc - v;
    off[i] = ex;
    cur[i] = ex;
  }
}

__global__ void k_fill(const int* __restrict__ src, const int* __restrict__ dst,
                       int* __restrict__ cur, int* __restrict__ esrc) {
  int stride = gridDim.x * blockDim.x;
  for (int e = blockIdx.x * blockDim.x + threadIdx.x; e < N_EDGES; e += stride) {
    int d = dst[e];
    int p = atomicAdd(&cur[d], 1);
    esrc[p] = src[e];
  }
}

// ---- f32 -> bf16 table conversion ------------------------------------------

__global__ void k_cvt(const float* __restrict__ in, unsigned short* __restrict__ outb) {
  int i = blockIdx.x * blockDim.x + threadIdx.x;
  const int n4 = (N_NODES * 64) / 4;
  if (i < n4) {
    float4 v = ((const float4*)in)[i];
    unsigned d0 = ((unsigned)f2bf(v.y) << 16) | f2bf(v.x);
    unsigned d1 = ((unsigned)f2bf(v.w) << 16) | f2bf(v.z);
    ((uint2*)outb)[i] = make_uint2(d0, d1);
  }
}

// ---- weight pre-swizzle into MFMA B-fragment order -------------------------
// B frag for 16x16x32: lane holds B[kc*32 + (lane>>4)*8 + j][nt*16 + (lane&15)], j=0..7
// stored at wf[mat] + ((kc*4+nt)*64 + lane)*8 ushorts (16 B per lane, coalesced)

__global__ void k_wprep(const float* __restrict__ W0, const float* __restrict__ W1,
                        const float* __restrict__ W2, const float* __restrict__ W3,
                        unsigned short* __restrict__ F) {
  const float* W = (blockIdx.x == 0) ? W0 : (blockIdx.x == 1) ? W1
                 : (blockIdx.x == 2) ? W2 : W3;
  unsigned short* out = F + blockIdx.x * 4096;  // 8 frags * 64 lanes * 8 elems
  int lane = threadIdx.x;
  int col = lane & 15, kr = lane >> 4;
  #pragma unroll
  for (int kc = 0; kc < 2; kc++)
    #pragma unroll
    for (int nt = 0; nt < 4; nt++) {
      unsigned d[4];
      #pragma unroll
      for (int jj = 0; jj < 4; jj++) {
        float w0 = W[(kc * 32 + kr * 8 + 2 * jj)     * 64 + nt * 16 + col];
        float w1 = W[(kc * 32 + kr * 8 + 2 * jj + 1) * 64 + nt * 16 + col];
        d[jj] = ((unsigned)f2bf(w1) << 16) | f2bf(w0);
      }
      uint4* p = (uint4*)(out + ((kc * 4 + nt) * 64 + lane) * 8);
      *p = make_uint4(d[0], d[1], d[2], d[3]);
    }
}

// ---- pure aggregation: mean of neighbor bf16 rows --------------------------
// wave per node; lane: r = lane>>3 edge slot, c = lane&7 feature octet (16 B)

__global__ void k_agg(const unsigned short* __restrict__ featb,
                      const int* __restrict__ off, const int* __restrict__ esrc,
                      unsigned short* __restrict__ aggb) {
  const int lane = threadIdx.x & 63;
  const int r = lane >> 3;
  const int c = lane & 7;
  const int wid = (blockIdx.x * blockDim.x + threadIdx.x) >> 6;
  const int nw  = (gridDim.x * blockDim.x) >> 6;

  for (int n = wid; n < N_NODES; n += nw) {
    const int o0 = off[n], o1 = off[n + 1];
    float acc[8];
    #pragma unroll
    for (int j = 0; j < 8; j++) acc[j] = 0.f;

    int i = o0;
    for (; i + 16 <= o1; i += 16) {
      int sA = esrc[i + r];
      int sB = esrc[i + 8 + r];
      uint4 vA = *(const uint4*)(featb + sA * 64 + c * 8);
      uint4 vB = *(const uint4*)(featb + sB * 64 + c * 8);
      acc[0] += bflo(vA.x); acc[1] += bfhi(vA.x);
      acc[2] += bflo(vA.y); acc[3] += bfhi(vA.y);
      acc[4] += bflo(vA.z); acc[5] += bfhi(vA.z);
      acc[6] += bflo(vA.w); acc[7] += bfhi(vA.w);
      acc[0] += bflo(vB.x); acc[1] += bfhi(vB.x);
      acc[2] += bflo(vB.y); acc[3] += bfhi(vB.y);
      acc[4] += bflo(vB.z); acc[5] += bfhi(vB.z);
      acc[6] += bflo(vB.w); acc[7] += bfhi(vB.w);
    }
    if (i + 8 <= o1) {
      int s = esrc[i + r];
      uint4 v = *(const uint4*)(featb + s * 64 + c * 8);
      acc[0] += bflo(v.x); acc[1] += bfhi(v.x);
      acc[2] += bflo(v.y); acc[3] += bfhi(v.y);
      acc[4] += bflo(v.z); acc[5] += bfhi(v.z);
      acc[6] += bflo(v.w); acc[7] += bfhi(v.w);
      i += 8;
    }
    if (i < o1) {
      int e = i + r;
      if (e < o1) {
        int s = esrc[e];
        uint4 v = *(const uint4*)(featb + s * 64 + c * 8);
        acc[0] += bflo(v.x); acc[1] += bfhi(v.x);
        acc[2] += bflo(v.y); acc[3] += bfhi(v.y);
        acc[4] += bflo(v.z); acc[5] += bfhi(v.z);
        acc[6] += bflo(v.w); acc[7] += bfhi(v.w);
      }
    }
    // reduce across the 8 edge-slot groups (lane bits 3..5)
    #pragma unroll
    for (int m = 8; m <= 32; m <<= 1)
      #pragma unroll
      for (int j = 0; j < 8; j++) acc[j] += __shfl_xor(acc[j], m);

    const int dg = o1 - o0;
    const float inv = (dg > 0) ? (1.0f / (float)dg) : 0.f;
    if (r == 0) {
      unsigned d0 = ((unsigned)f2bf(acc[1] * inv) << 16) | f2bf(acc[0] * inv);
      unsigned d1 = ((unsigned)f2bf(acc[3] * inv) << 16) | f2bf(acc[2] * inv);
      unsigned d2 = ((unsigned)f2bf(acc[5] * inv) << 16) | f2bf(acc[4] * inv);
      unsigned d3 = ((unsigned)f2bf(acc[7] * inv) << 16) | f2bf(acc[6] * inv);
      *(uint4*)(aggb + n * 64 + c * 8) = make_uint4(d0, d1, d2, d3);
    }
  }
}

// ---- MFMA transform: out = self@Ws + agg@Wn + b ----------------------------

template <bool RELU, bool OUT_BF>
__global__ void k_xform(const unsigned short* __restrict__ selfb,
                        const unsigned short* __restrict__ aggb,
                        const unsigned short* __restrict__ wfS,
                        const unsigned short* __restrict__ wfN,
                        const float* __restrict__ bias,
                        float* __restrict__ outf, unsigned short* __restrict__ outb) {
  const int lane = threadIdx.x & 63;
  const int col = lane & 15, rr = lane >> 4;
  const int wid = (blockIdx.x * blockDim.x + threadIdx.x) >> 6;
  const int nw  = (gridDim.x * blockDim.x) >> 6;

  short8 bs[2][4], bn[2][4];
  #pragma unroll
  for (int kc = 0; kc < 2; kc++)
    #pragma unroll
    for (int nt = 0; nt < 4; nt++) {
      bs[kc][nt] = *(const short8*)(wfS + ((kc * 4 + nt) * 64 + lane) * 8);
      bn[kc][nt] = *(const short8*)(wfN + ((kc * 4 + nt) * 64 + lane) * 8);
    }
  float bv[4];
  #pragma unroll
  for (int nt = 0; nt < 4; nt++) bv[nt] = bias[nt * 16 + col];

  const int NT = N_NODES / 16;  // 6250, exact
  for (int t = wid; t < NT; t += nw) {
    const int m = t * 16 + col;  // A row (m = lane&15)
    short8 as0 = *(const short8*)(selfb + m * 64 + rr * 8);
    short8 as1 = *(const short8*)(selfb + m * 64 + 32 + rr * 8);
    short8 aa0 = *(const short8*)(aggb + m * 64 + rr * 8);
    short8 aa1 = *(const short8*)(aggb + m * 64 + 32 + rr * 8);
    #pragma unroll
    for (int nt = 0; nt < 4; nt++) {
      float4v cfr = {bv[nt], bv[nt], bv[nt], bv[nt]};
      cfr = __builtin_amdgcn_mfma_f32_16x16x32_bf16(as0, bs[0][nt], cfr, 0, 0, 0);
      cfr = __builtin_amdgcn_mfma_f32_16x16x32_bf16(as1, bs[1][nt], cfr, 0, 0, 0);
      cfr = __builtin_amdgcn_mfma_f32_16x16x32_bf16(aa0, bn[0][nt], cfr, 0, 0, 0);
      cfr = __builtin_amdgcn_mfma_f32_16x16x32_bf16(aa1, bn[1][nt], cfr, 0, 0, 0);
      #pragma unroll
      for (int r2 = 0; r2 < 4; r2++) {
        int row = t * 16 + rr * 4 + r2;  // C/D: row=(lane>>4)*4+reg, col=lane&15
        float v = cfr[r2];
        if (RELU) v = fmaxf(v, 0.f);
        if (OUT_BF) outb[row * 64 + nt * 16 + col] = f2bf(v);
        else        outf[row * 64 + nt * 16 + col] = v;
      }
    }
  }
}

// ---- launch ----------------------------------------------------------------

extern "C" void kernel_launch(void* const* d_in, const int* in_sizes, int n_in,
                              void* d_out, int out_size, void* d_ws, size_t ws_size,
                              hipStream_t stream) {
  const float* x   = (const float*)d_in[0];
  const int*   src = (const int*)d_in[1];
  const int*   dst = (const int*)d_in[2];
  const float* Ws1 = (const float*)d_in[3];
  const float* Wn1 = (const float*)d_in[4];
  const float* b1  = (const float*)d_in[5];
  const float* Ws2 = (const float*)d_in[6];
  const float* Wn2 = (const float*)d_in[7];
  const float* b2  = (const float*)d_in[8];

  char* ws = (char*)d_ws;
  int*            deg  = (int*)(ws + 0);          // N ints
  int*            off  = (int*)(ws + 400128);     // N+1 ints
  int*            cur  = (int*)(ws + 800512);     // N ints
  int*            bsum = (int*)(ws + 1200640);    // ~400 ints
  int*            esrc = (int*)(ws + 1202688);    // E ints, ends 7602688
  unsigned short* wf   = (unsigned short*)(ws + 7602688);   // 4 * 8 KB frag-order weights
  unsigned short* xbf  = (unsigned short*)(ws + 7635456);   // N*64 bf16
  unsigned short* hbf  = (unsigned short*)(ws + 20435456);  // N*64 bf16, ends 33235456

  unsigned short* agg1 = (unsigned short*)d_out;  // scratch inside d_out (12.8 of 25.6 MB)
  unsigned short* agg2 = xbf;                     // reuse after layer-1 transform

  const int NB = (N_NODES + 255) / 256;  // 391

  hipMemsetAsync(deg, 0, N_NODES * sizeof(int), stream);
  k_hist<<<2048, 256, 0, stream>>>(dst, deg);
  k_blocksum<<<NB, 256, 0, stream>>>(deg, bsum);
  k_scan_bsum<<<1, 64, 0, stream>>>(bsum, NB, off);
  k_offsets<<<NB, 256, 0, stream>>>(deg, bsum, off, cur);
  k_fill<<<2048, 256, 0, stream>>>(src, dst, cur, esrc);
  k_cvt<<<(N_NODES * 16 + 255) / 256, 256, 0, stream>>>(x, xbf);
  k_wprep<<<4, 64, 0, stream>>>(Ws1, Wn1, Ws2, Wn2, wf);

  k_agg<<<2048, 256, 0, stream>>>(xbf, off, esrc, agg1);
  k_xform<true, true><<<1024, 256, 0, stream>>>(xbf, agg1, wf + 0 * 4096, wf + 1 * 4096,
                                                b1, nullptr, hbf);
  k_agg<<<2048, 256, 0, stream>>>(hbf, off, esrc, agg2);
  k_xform<false, false><<<1024, 256, 0, stream>>>(hbf, agg2, wf + 2 * 4096, wf + 3 * 4096,
                                                  b2, (float*)d_out, nullptr);
}

// Round 5
// 331.868 us; speedup vs baseline: 2.3870x; 1.1815x over previous
//
#include <hip/hip_runtime.h>

#define N_NODES 100000
#define N_EDGES 1600000
#define NBKT 196          // ceil(100000 / 512)
#define BKT_SHIFT 9
#define BKT_MASK 511

typedef __attribute__((ext_vector_type(8))) short short8;
typedef __attribute__((ext_vector_type(4))) float float4v;

__device__ __forceinline__ unsigned short f2bf(float f) {  // RNE
  unsigned u = __float_as_uint(f);
  return (unsigned short)((u + 0x7fffu + ((u >> 16) & 1u)) >> 16);
}
__device__ __forceinline__ float bflo(unsigned d) { return __uint_as_float(d << 16); }
__device__ __forceinline__ float bfhi(unsigned d) { return __uint_as_float(d & 0xffff0000u); }

// ---- degree / offsets (unchanged) ------------------------------------------

__global__ void k_hist(const int* __restrict__ dst, int* __restrict__ deg) {
  int stride = gridDim.x * blockDim.x;
  for (int e = blockIdx.x * blockDim.x + threadIdx.x; e < N_EDGES; e += stride)
    atomicAdd(&deg[dst[e]], 1);
}

__global__ void k_blocksum(const int* __restrict__ deg, int* __restrict__ bsum) {
  int i = blockIdx.x * 256 + threadIdx.x;
  int v = (i < N_NODES) ? deg[i] : 0;
  #pragma unroll
  for (int d = 32; d; d >>= 1) v += __shfl_down(v, d);
  __shared__ int wsum[4];
  if ((threadIdx.x & 63) == 0) wsum[threadIdx.x >> 6] = v;
  __syncthreads();
  if (threadIdx.x == 0) bsum[blockIdx.x] = wsum[0] + wsum[1] + wsum[2] + wsum[3];
}

__global__ void k_scan_bsum(int* __restrict__ bsum, int nb, int* __restrict__ off) {
  int lane = threadIdx.x;
  int running = 0;
  for (int base = 0; base < nb; base += 64) {
    int i = base + lane;
    int v = (i < nb) ? bsum[i] : 0;
    int inc = v;
    #pragma unroll
    for (int d = 1; d < 64; d <<= 1) { int y = __shfl_up(inc, d); if (lane >= d) inc += y; }
    if (i < nb) bsum[i] = running + inc - v;
    running += __shfl(inc, 63);
  }
  if (lane == 0) off[N_NODES] = running;
}

__global__ void k_offsets(const int* __restrict__ deg, const int* __restrict__ bsum,
                          int* __restrict__ off, int* __restrict__ cur) {
  int i = blockIdx.x * 256 + threadIdx.x;
  int lane = threadIdx.x & 63, w = threadIdx.x >> 6;
  int v = (i < N_NODES) ? deg[i] : 0;
  int inc = v;
  #pragma unroll
  for (int d = 1; d < 64; d <<= 1) { int y = __shfl_up(inc, d); if (lane >= d) inc += y; }
  __shared__ int wtot[4];
  if (lane == 63) wtot[w] = inc;
  __syncthreads();
  int base = bsum[blockIdx.x];
  for (int j = 0; j < w; j++) base += wtot[j];
  if (i < N_NODES) {
    int ex = base + inc - v;
    off[i] = ex;
    cur[i] = ex;
  }
}

// ---- two-level binned edge scatter (replaces k_fill) -----------------------

__global__ void kA_count(const int* __restrict__ dst, int* __restrict__ blkCnt) {
  __shared__ int hist[NBKT];
  for (int t = threadIdx.x; t < NBKT; t += 256) hist[t] = 0;
  __syncthreads();
  const int chunk = (N_EDGES + gridDim.x - 1) / gridDim.x;
  const int e0 = blockIdx.x * chunk;
  const int e1 = min(e0 + chunk, N_EDGES);
  for (int e = e0 + threadIdx.x; e < e1; e += 256)
    atomicAdd(&hist[dst[e] >> BKT_SHIFT], 1);
  __syncthreads();
  for (int t = threadIdx.x; t < NBKT; t += 256)
    blkCnt[t * 256 + blockIdx.x] = hist[t];
}

// one block per bucket: exclusive scan of the 256 per-block counts
__global__ void kA_scan1(int* __restrict__ blkCnt, int* __restrict__ bktTot) {
  const int b = blockIdx.x;
  const int tid = threadIdx.x, lane = tid & 63, w = tid >> 6;
  int v = blkCnt[b * 256 + tid];
  int inc = v;
  #pragma unroll
  for (int d = 1; d < 64; d <<= 1) { int y = __shfl_up(inc, d); if (lane >= d) inc += y; }
  __shared__ int wtot[4];
  if (lane == 63) wtot[w] = inc;
  __syncthreads();
  int base = 0;
  for (int j = 0; j < w; j++) base += wtot[j];
  blkCnt[b * 256 + tid] = base + inc - v;  // bucket-relative exclusive position
  if (tid == 255) bktTot[b] = base + inc;
}

__global__ void kA_scan2(const int* __restrict__ bktTot, int* __restrict__ bktStart) {
  int lane = threadIdx.x;
  int running = 0;
  for (int base = 0; base < NBKT; base += 64) {
    int i = base + lane;
    int v = (i < NBKT) ? bktTot[i] : 0;
    int inc = v;
    #pragma unroll
    for (int d = 1; d < 64; d <<= 1) { int y = __shfl_up(inc, d); if (lane >= d) inc += y; }
    if (i < NBKT) bktStart[i] = running + inc - v;
    running += __shfl(inc, 63);
  }
}

__global__ void kA_scatter(const int* __restrict__ src, const int* __restrict__ dst,
                           const int* __restrict__ blkCnt, const int* __restrict__ bktStart,
                           int* __restrict__ binned) {
  __shared__ int curb[NBKT];
  for (int t = threadIdx.x; t < NBKT; t += 256)
    curb[t] = bktStart[t] + blkCnt[t * 256 + blockIdx.x];
  __syncthreads();
  const int chunk = (N_EDGES + gridDim.x - 1) / gridDim.x;
  const int e0 = blockIdx.x * chunk;
  const int e1 = min(e0 + chunk, N_EDGES);
  for (int e = e0 + threadIdx.x; e < e1; e += 256) {
    int d = dst[e];
    int s = src[e];
    int b = d >> BKT_SHIFT;
    int p = atomicAdd(&curb[b], 1);
    binned[p] = s | ((d & BKT_MASK) << 17);
  }
}

// one block per bucket: exact per-dst placement, all traffic bucket-local
__global__ void kB_scatter(const int* __restrict__ binned, const int* __restrict__ bktStart,
                           const int* __restrict__ bktTot, int* __restrict__ cur,
                           int* __restrict__ esrc) {
  const int b = blockIdx.x;
  const int s0 = bktStart[b], cnt = bktTot[b];
  const int base = b << BKT_SHIFT;
  for (int i = threadIdx.x; i < cnt; i += blockDim.x) {
    int pe = binned[s0 + i];
    int s = pe & 0x1FFFF;
    int d = base + (pe >> 17);
    int p = atomicAdd(&cur[d], 1);
    esrc[p] = s;
  }
}

// ---- f32 -> bf16 table conversion ------------------------------------------

__global__ void k_cvt(const float* __restrict__ in, unsigned short* __restrict__ outb) {
  int i = blockIdx.x * blockDim.x + threadIdx.x;
  const int n4 = (N_NODES * 64) / 4;
  if (i < n4) {
    float4 v = ((const float4*)in)[i];
    unsigned d0 = ((unsigned)f2bf(v.y) << 16) | f2bf(v.x);
    unsigned d1 = ((unsigned)f2bf(v.w) << 16) | f2bf(v.z);
    ((uint2*)outb)[i] = make_uint2(d0, d1);
  }
}

// ---- weight pre-swizzle into MFMA B-fragment order -------------------------

__global__ void k_wprep(const float* __restrict__ W0, const float* __restrict__ W1,
                        const float* __restrict__ W2, const float* __restrict__ W3,
                        unsigned short* __restrict__ F) {
  const float* W = (blockIdx.x == 0) ? W0 : (blockIdx.x == 1) ? W1
                 : (blockIdx.x == 2) ? W2 : W3;
  unsigned short* out = F + blockIdx.x * 4096;
  int lane = threadIdx.x;
  int col = lane & 15, kr = lane >> 4;
  #pragma unroll
  for (int kc = 0; kc < 2; kc++)
    #pragma unroll
    for (int nt = 0; nt < 4; nt++) {
      unsigned d[4];
      #pragma unroll
      for (int jj = 0; jj < 4; jj++) {
        float w0 = W[(kc * 32 + kr * 8 + 2 * jj)     * 64 + nt * 16 + col];
        float w1 = W[(kc * 32 + kr * 8 + 2 * jj + 1) * 64 + nt * 16 + col];
        d[jj] = ((unsigned)f2bf(w1) << 16) | f2bf(w0);
      }
      uint4* p = (uint4*)(out + ((kc * 4 + nt) * 64 + lane) * 8);
      *p = make_uint4(d[0], d[1], d[2], d[3]);
    }
}

// ---- pure aggregation: mean of neighbor bf16 rows (unchanged) --------------

__global__ void k_agg(const unsigned short* __restrict__ featb,
                      const int* __restrict__ off, const int* __restrict__ esrc,
                      unsigned short* __restrict__ aggb) {
  const int lane = threadIdx.x & 63;
  const int r = lane >> 3;
  const int c = lane & 7;
  const int wid = (blockIdx.x * blockDim.x + threadIdx.x) >> 6;
  const int nw  = (gridDim.x * blockDim.x) >> 6;

  for (int n = wid; n < N_NODES; n += nw) {
    const int o0 = off[n], o1 = off[n + 1];
    float acc[8];
    #pragma unroll
    for (int j = 0; j < 8; j++) acc[j] = 0.f;

    int i = o0;
    for (; i + 16 <= o1; i += 16) {
      int sA = esrc[i + r];
      int sB = esrc[i + 8 + r];
      uint4 vA = *(const uint4*)(featb + sA * 64 + c * 8);
      uint4 vB = *(const uint4*)(featb + sB * 64 + c * 8);
      acc[0] += bflo(vA.x); acc[1] += bfhi(vA.x);
      acc[2] += bflo(vA.y); acc[3] += bfhi(vA.y);
      acc[4] += bflo(vA.z); acc[5] += bfhi(vA.z);
      acc[6] += bflo(vA.w); acc[7] += bfhi(vA.w);
      acc[0] += bflo(vB.x); acc[1] += bfhi(vB.x);
      acc[2] += bflo(vB.y); acc[3] += bfhi(vB.y);
      acc[4] += bflo(vB.z); acc[5] += bfhi(vB.z);
      acc[6] += bflo(vB.w); acc[7] += bfhi(vB.w);
    }
    if (i + 8 <= o1) {
      int s = esrc[i + r];
      uint4 v = *(const uint4*)(featb + s * 64 + c * 8);
      acc[0] += bflo(v.x); acc[1] += bfhi(v.x);
      acc[2] += bflo(v.y); acc[3] += bfhi(v.y);
      acc[4] += bflo(v.z); acc[5] += bfhi(v.z);
      acc[6] += bflo(v.w); acc[7] += bfhi(v.w);
      i += 8;
    }
    if (i < o1) {
      int e = i + r;
      if (e < o1) {
        int s = esrc[e];
        uint4 v = *(const uint4*)(featb + s * 64 + c * 8);
        acc[0] += bflo(v.x); acc[1] += bfhi(v.x);
        acc[2] += bflo(v.y); acc[3] += bfhi(v.y);
        acc[4] += bflo(v.z); acc[5] += bfhi(v.z);
        acc[6] += bflo(v.w); acc[7] += bfhi(v.w);
      }
    }
    #pragma unroll
    for (int m = 8; m <= 32; m <<= 1)
      #pragma unroll
      for (int j = 0; j < 8; j++) acc[j] += __shfl_xor(acc[j], m);

    const int dg = o1 - o0;
    const float inv = (dg > 0) ? (1.0f / (float)dg) : 0.f;
    if (r == 0) {
      unsigned d0 = ((unsigned)f2bf(acc[1] * inv) << 16) | f2bf(acc[0] * inv);
      unsigned d1 = ((unsigned)f2bf(acc[3] * inv) << 16) | f2bf(acc[2] * inv);
      unsigned d2 = ((unsigned)f2bf(acc[5] * inv) << 16) | f2bf(acc[4] * inv);
      unsigned d3 = ((unsigned)f2bf(acc[7] * inv) << 16) | f2bf(acc[6] * inv);
      *(uint4*)(aggb + n * 64 + c * 8) = make_uint4(d0, d1, d2, d3);
    }
  }
}

// ---- MFMA transform (unchanged) --------------------------------------------

template <bool RELU, bool OUT_BF>
__global__ void k_xform(const unsigned short* __restrict__ selfb,
                        const unsigned short* __restrict__ aggb,
                        const unsigned short* __restrict__ wfS,
                        const unsigned short* __restrict__ wfN,
                        const float* __restrict__ bias,
                        float* __restrict__ outf, unsigned short* __restrict__ outb) {
  const int lane = threadIdx.x & 63;
  const int col = lane & 15, rr = lane >> 4;
  const int wid = (blockIdx.x * blockDim.x + threadIdx.x) >> 6;
  const int nw  = (gridDim.x * blockDim.x) >> 6;

  short8 bs[2][4], bn[2][4];
  #pragma unroll
  for (int kc = 0; kc < 2; kc++)
    #pragma unroll
    for (int nt = 0; nt < 4; nt++) {
      bs[kc][nt] = *(const short8*)(wfS + ((kc * 4 + nt) * 64 + lane) * 8);
      bn[kc][nt] = *(const short8*)(wfN + ((kc * 4 + nt) * 64 + lane) * 8);
    }
  float bv[4];
  #pragma unroll
  for (int nt = 0; nt < 4; nt++) bv[nt] = bias[nt * 16 + col];

  const int NT = N_NODES / 16;  // 6250
  for (int t = wid; t < NT; t += nw) {
    const int m = t * 16 + col;
    short8 as0 = *(const short8*)(selfb + m * 64 + rr * 8);
    short8 as1 = *(const short8*)(selfb + m * 64 + 32 + rr * 8);
    short8 aa0 = *(const short8*)(aggb + m * 64 + rr * 8);
    short8 aa1 = *(const short8*)(aggb + m * 64 + 32 + rr * 8);
    #pragma unroll
    for (int nt = 0; nt < 4; nt++) {
      float4v cfr = {bv[nt], bv[nt], bv[nt], bv[nt]};
      cfr = __builtin_amdgcn_mfma_f32_16x16x32_bf16(as0, bs[0][nt], cfr, 0, 0, 0);
      cfr = __builtin_amdgcn_mfma_f32_16x16x32_bf16(as1, bs[1][nt], cfr, 0, 0, 0);
      cfr = __builtin_amdgcn_mfma_f32_16x16x32_bf16(aa0, bn[0][nt], cfr, 0, 0, 0);
      cfr = __builtin_amdgcn_mfma_f32_16x16x32_bf16(aa1, bn[1][nt], cfr, 0, 0, 0);
      #pragma unroll
      for (int r2 = 0; r2 < 4; r2++) {
        int row = t * 16 + rr * 4 + r2;
        float v = cfr[r2];
        if (RELU) v = fmaxf(v, 0.f);
        if (OUT_BF) outb[row * 64 + nt * 16 + col] = f2bf(v);
        else        outf[row * 64 + nt * 16 + col] = v;
      }
    }
  }
}

// ---- launch ----------------------------------------------------------------

extern "C" void kernel_launch(void* const* d_in, const int* in_sizes, int n_in,
                              void* d_out, int out_size, void* d_ws, size_t ws_size,
                              hipStream_t stream) {
  const float* x   = (const float*)d_in[0];
  const int*   src = (const int*)d_in[1];
  const int*   dst = (const int*)d_in[2];
  const float* Ws1 = (const float*)d_in[3];
  const float* Wn1 = (const float*)d_in[4];
  const float* b1  = (const float*)d_in[5];
  const float* Ws2 = (const float*)d_in[6];
  const float* Wn2 = (const float*)d_in[7];
  const float* b2  = (const float*)d_in[8];

  char* ws = (char*)d_ws;
  int*            deg  = (int*)(ws + 0);
  int*            off  = (int*)(ws + 400128);
  int*            cur  = (int*)(ws + 800512);
  int*            bsum = (int*)(ws + 1200640);
  int*            esrc = (int*)(ws + 1202688);              // E ints, ends 7602688
  unsigned short* wf   = (unsigned short*)(ws + 7602688);   // 32 KB frag weights
  unsigned short* xbf  = (unsigned short*)(ws + 7635456);   // N*64 bf16
  unsigned short* hbf  = (unsigned short*)(ws + 20435456);  // N*64 bf16, ends 33235456
  int*            binned = (int*)(ws + 20435456);           // E ints, aliases hbf (consumed first)

  // scratch in upper half of d_out (free until final k_xform writes it)
  char* dox = (char*)d_out;
  int* blkCnt   = (int*)(dox + 13000000);  // NBKT*256 ints = 200704 B
  int* bktTot   = (int*)(dox + 13300000);  // NBKT ints
  int* bktStart = (int*)(dox + 13400000);  // NBKT ints

  unsigned short* agg1 = (unsigned short*)d_out;  // first 12.8 MB of d_out
  unsigned short* agg2 = xbf;                     // reuse after layer-1 transform

  const int NB = (N_NODES + 255) / 256;  // 391

  hipMemsetAsync(deg, 0, N_NODES * sizeof(int), stream);
  k_hist<<<2048, 256, 0, stream>>>(dst, deg);
  k_blocksum<<<NB, 256, 0, stream>>>(deg, bsum);
  k_scan_bsum<<<1, 64, 0, stream>>>(bsum, NB, off);
  k_offsets<<<NB, 256, 0, stream>>>(deg, bsum, off, cur);

  kA_count<<<256, 256, 0, stream>>>(dst, blkCnt);
  kA_scan1<<<NBKT, 256, 0, stream>>>(blkCnt, bktTot);
  kA_scan2<<<1, 64, 0, stream>>>(bktTot, bktStart);
  kA_scatter<<<256, 256, 0, stream>>>(src, dst, blkCnt, bktStart, binned);
  kB_scatter<<<NBKT, 256, 0, stream>>>(binned, bktStart, bktTot, cur, esrc);

  k_cvt<<<(N_NODES * 16 + 255) / 256, 256, 0, stream>>>(x, xbf);
  k_wprep<<<4, 64, 0, stream>>>(Ws1, Wn1, Ws2, Wn2, wf);

  k_agg<<<2048, 256, 0, stream>>>(xbf, off, esrc, agg1);
  k_xform<true, true><<<1024, 256, 0, stream>>>(xbf, agg1, wf + 0 * 4096, wf + 1 * 4096,
                                                b1, nullptr, hbf);
  k_agg<<<2048, 256, 0, stream>>>(hbf, off, esrc, agg2);
  k_xform<false, false><<<1024, 256, 0, stream>>>(hbf, agg2, wf + 2 * 4096, wf + 3 * 4096,
                                                  b2, (float*)d_out, nullptr);
}

// Round 6
// 266.691 us; speedup vs baseline: 2.9703x; 1.2444x over previous
//
#include <hip/hip_runtime.h>

#define N_NODES 100000
#define N_EDGES 1600000
#define NBKT 196          // ceil(100000 / 512)
#define BKT_SHIFT 9
#define BKT_MASK 511

typedef __attribute__((ext_vector_type(8))) short short8;
typedef __attribute__((ext_vector_type(4))) float float4v;

__device__ __forceinline__ unsigned short f2bf(float f) {  // RNE
  unsigned u = __float_as_uint(f);
  return (unsigned short)((u + 0x7fffu + ((u >> 16) & 1u)) >> 16);
}
__device__ __forceinline__ float bflo(unsigned d) { return __uint_as_float(d << 16); }
__device__ __forceinline__ float bfhi(unsigned d) { return __uint_as_float(d & 0xffff0000u); }

// ---- two-level binned edge scatter ----------------------------------------

__global__ void kA_count(const int* __restrict__ dst, int* __restrict__ blkCnt) {
  __shared__ int hist[NBKT];
  for (int t = threadIdx.x; t < NBKT; t += 256) hist[t] = 0;
  __syncthreads();
  const int chunk = (N_EDGES + gridDim.x - 1) / gridDim.x;
  const int e0 = blockIdx.x * chunk;
  const int e1 = min(e0 + chunk, N_EDGES);
  for (int e = e0 + threadIdx.x; e < e1; e += 256)
    atomicAdd(&hist[dst[e] >> BKT_SHIFT], 1);
  __syncthreads();
  for (int t = threadIdx.x; t < NBKT; t += 256)
    blkCnt[t * 256 + blockIdx.x] = hist[t];
}

// one block per bucket: exclusive scan of the 256 per-block counts
__global__ void kA_scan1(int* __restrict__ blkCnt, int* __restrict__ bktTot) {
  const int b = blockIdx.x;
  const int tid = threadIdx.x, lane = tid & 63, w = tid >> 6;
  int v = blkCnt[b * 256 + tid];
  int inc = v;
  #pragma unroll
  for (int d = 1; d < 64; d <<= 1) { int y = __shfl_up(inc, d); if (lane >= d) inc += y; }
  __shared__ int wtot[4];
  if (lane == 63) wtot[w] = inc;
  __syncthreads();
  int base = 0;
  for (int j = 0; j < w; j++) base += wtot[j];
  blkCnt[b * 256 + tid] = base + inc - v;
  if (tid == 255) bktTot[b] = base + inc;
}

__global__ void kA_scan2(const int* __restrict__ bktTot, int* __restrict__ bktStart) {
  int lane = threadIdx.x;
  int running = 0;
  for (int base = 0; base < NBKT; base += 64) {
    int i = base + lane;
    int v = (i < NBKT) ? bktTot[i] : 0;
    int inc = v;
    #pragma unroll
    for (int d = 1; d < 64; d <<= 1) { int y = __shfl_up(inc, d); if (lane >= d) inc += y; }
    if (i < NBKT) bktStart[i] = running + inc - v;
    running += __shfl(inc, 63);
  }
}

__global__ void kA_scatter(const int* __restrict__ src, const int* __restrict__ dst,
                           const int* __restrict__ blkCnt, const int* __restrict__ bktStart,
                           int* __restrict__ binned) {
  __shared__ int curb[NBKT];
  for (int t = threadIdx.x; t < NBKT; t += 256)
    curb[t] = bktStart[t] + blkCnt[t * 256 + blockIdx.x];
  __syncthreads();
  const int chunk = (N_EDGES + gridDim.x - 1) / gridDim.x;
  const int e0 = blockIdx.x * chunk;
  const int e1 = min(e0 + chunk, N_EDGES);
  for (int e = e0 + threadIdx.x; e < e1; e += 256) {
    int d = dst[e];
    int s = src[e];
    int b = d >> BKT_SHIFT;
    int p = atomicAdd(&curb[b], 1);
    binned[p] = s | ((d & BKT_MASK) << 17);
  }
}

// one block per bucket: LDS degree histogram + local scan -> off/cur directly
__global__ void k_degoff(const int* __restrict__ binned, const int* __restrict__ bktStart,
                         const int* __restrict__ bktTot,
                         int* __restrict__ off, int* __restrict__ cur) {
  const int b = blockIdx.x;
  const int tid = threadIdx.x, lane = tid & 63, w = tid >> 6;
  __shared__ int cnt[512];
  cnt[tid] = 0; cnt[tid + 256] = 0;
  __syncthreads();
  const int s0 = bktStart[b], n_e = bktTot[b];
  for (int i = tid; i < n_e; i += 256)
    atomicAdd(&cnt[binned[s0 + i] >> 17], 1);
  __syncthreads();
  // scan 512 counters: thread t owns elements 2t, 2t+1
  int c0 = cnt[2 * tid], c1 = cnt[2 * tid + 1];
  int v = c0 + c1;
  int inc = v;
  #pragma unroll
  for (int d = 1; d < 64; d <<= 1) { int y = __shfl_up(inc, d); if (lane >= d) inc += y; }
  __shared__ int wtot[4];
  if (lane == 63) wtot[w] = inc;
  __syncthreads();
  int base = s0;
  for (int j = 0; j < w; j++) base += wtot[j];
  int ex = base + inc - v;  // global edge offset of node (b<<9)+2t
  int n0 = (b << BKT_SHIFT) + 2 * tid;
  if (n0 < N_NODES)     { off[n0] = ex;          cur[n0] = ex; }
  if (n0 + 1 < N_NODES) { off[n0 + 1] = ex + c0; cur[n0 + 1] = ex + c0; }
  if (b == NBKT - 1 && tid == 0) off[N_NODES] = N_EDGES;
}

// one block per bucket: exact per-dst placement, all traffic bucket-local
__global__ void kB_scatter(const int* __restrict__ binned, const int* __restrict__ bktStart,
                           const int* __restrict__ bktTot, int* __restrict__ cur,
                           int* __restrict__ esrc) {
  const int b = blockIdx.x;
  const int s0 = bktStart[b], cnt = bktTot[b];
  const int base = b << BKT_SHIFT;
  for (int i = threadIdx.x; i < cnt; i += blockDim.x) {
    int pe = binned[s0 + i];
    int s = pe & 0x1FFFF;
    int d = base + (pe >> 17);
    int p = atomicAdd(&cur[d], 1);
    esrc[p] = s;
  }
}

// ---- f32 -> bf16 table conversion ------------------------------------------

__global__ void k_cvt(const float* __restrict__ in, unsigned short* __restrict__ outb) {
  int i = blockIdx.x * blockDim.x + threadIdx.x;
  const int n4 = (N_NODES * 64) / 4;
  if (i < n4) {
    float4 v = ((const float4*)in)[i];
    unsigned d0 = ((unsigned)f2bf(v.y) << 16) | f2bf(v.x);
    unsigned d1 = ((unsigned)f2bf(v.w) << 16) | f2bf(v.z);
    ((uint2*)outb)[i] = make_uint2(d0, d1);
  }
}

// ---- weight pre-swizzle into MFMA B-fragment order -------------------------

__global__ void k_wprep(const float* __restrict__ W0, const float* __restrict__ W1,
                        const float* __restrict__ W2, const float* __restrict__ W3,
                        unsigned short* __restrict__ F) {
  const float* W = (blockIdx.x == 0) ? W0 : (blockIdx.x == 1) ? W1
                 : (blockIdx.x == 2) ? W2 : W3;
  unsigned short* out = F + blockIdx.x * 4096;
  int lane = threadIdx.x;
  int col = lane & 15, kr = lane >> 4;
  #pragma unroll
  for (int kc = 0; kc < 2; kc++)
    #pragma unroll
    for (int nt = 0; nt < 4; nt++) {
      unsigned d[4];
      #pragma unroll
      for (int jj = 0; jj < 4; jj++) {
        float w0 = W[(kc * 32 + kr * 8 + 2 * jj)     * 64 + nt * 16 + col];
        float w1 = W[(kc * 32 + kr * 8 + 2 * jj + 1) * 64 + nt * 16 + col];
        d[jj] = ((unsigned)f2bf(w1) << 16) | f2bf(w0);
      }
      uint4* p = (uint4*)(out + ((kc * 4 + nt) * 64 + lane) * 8);
      *p = make_uint4(d[0], d[1], d[2], d[3]);
    }
}

// ---- pure aggregation: mean of neighbor bf16 rows --------------------------

__global__ void k_agg(const unsigned short* __restrict__ featb,
                      const int* __restrict__ off, const int* __restrict__ esrc,
                      unsigned short* __restrict__ aggb) {
  const int lane = threadIdx.x & 63;
  const int r = lane >> 3;
  const int c = lane & 7;
  const int wid = (blockIdx.x * blockDim.x + threadIdx.x) >> 6;
  const int nw  = (gridDim.x * blockDim.x) >> 6;

  for (int n = wid; n < N_NODES; n += nw) {
    const int o0 = off[n], o1 = off[n + 1];
    float acc[8];
    #pragma unroll
    for (int j = 0; j < 8; j++) acc[j] = 0.f;

    int i = o0;
    for (; i + 16 <= o1; i += 16) {
      int sA = esrc[i + r];
      int sB = esrc[i + 8 + r];
      uint4 vA = *(const uint4*)(featb + sA * 64 + c * 8);
      uint4 vB = *(const uint4*)(featb + sB * 64 + c * 8);
      acc[0] += bflo(vA.x); acc[1] += bfhi(vA.x);
      acc[2] += bflo(vA.y); acc[3] += bfhi(vA.y);
      acc[4] += bflo(vA.z); acc[5] += bfhi(vA.z);
      acc[6] += bflo(vA.w); acc[7] += bfhi(vA.w);
      acc[0] += bflo(vB.x); acc[1] += bfhi(vB.x);
      acc[2] += bflo(vB.y); acc[3] += bfhi(vB.y);
      acc[4] += bflo(vB.z); acc[5] += bfhi(vB.z);
      acc[6] += bflo(vB.w); acc[7] += bfhi(vB.w);
    }
    if (i + 8 <= o1) {
      int s = esrc[i + r];
      uint4 v = *(const uint4*)(featb + s * 64 + c * 8);
      acc[0] += bflo(v.x); acc[1] += bfhi(v.x);
      acc[2] += bflo(v.y); acc[3] += bfhi(v.y);
      acc[4] += bflo(v.z); acc[5] += bfhi(v.z);
      acc[6] += bflo(v.w); acc[7] += bfhi(v.w);
      i += 8;
    }
    if (i < o1) {
      int e = i + r;
      if (e < o1) {
        int s = esrc[e];
        uint4 v = *(const uint4*)(featb + s * 64 + c * 8);
        acc[0] += bflo(v.x); acc[1] += bfhi(v.x);
        acc[2] += bflo(v.y); acc[3] += bfhi(v.y);
        acc[4] += bflo(v.z); acc[5] += bfhi(v.z);
        acc[6] += bflo(v.w); acc[7] += bfhi(v.w);
      }
    }
    #pragma unroll
    for (int m = 8; m <= 32; m <<= 1)
      #pragma unroll
      for (int j = 0; j < 8; j++) acc[j] += __shfl_xor(acc[j], m);

    const int dg = o1 - o0;
    const float inv = (dg > 0) ? (1.0f / (float)dg) : 0.f;
    if (r == 0) {
      unsigned d0 = ((unsigned)f2bf(acc[1] * inv) << 16) | f2bf(acc[0] * inv);
      unsigned d1 = ((unsigned)f2bf(acc[3] * inv) << 16) | f2bf(acc[2] * inv);
      unsigned d2 = ((unsigned)f2bf(acc[5] * inv) << 16) | f2bf(acc[4] * inv);
      unsigned d3 = ((unsigned)f2bf(acc[7] * inv) << 16) | f2bf(acc[6] * inv);
      *(uint4*)(aggb + n * 64 + c * 8) = make_uint4(d0, d1, d2, d3);
    }
  }
}

// ---- MFMA transform --------------------------------------------------------

template <bool RELU, bool OUT_BF>
__global__ void k_xform(const unsigned short* __restrict__ selfb,
                        const unsigned short* __restrict__ aggb,
                        const unsigned short* __restrict__ wfS,
                        const unsigned short* __restrict__ wfN,
                        const float* __restrict__ bias,
                        float* __restrict__ outf, unsigned short* __restrict__ outb) {
  const int lane = threadIdx.x & 63;
  const int col = lane & 15, rr = lane >> 4;
  const int wid = (blockIdx.x * blockDim.x + threadIdx.x) >> 6;
  const int nw  = (gridDim.x * blockDim.x) >> 6;

  short8 bs[2][4], bn[2][4];
  #pragma unroll
  for (int kc = 0; kc < 2; kc++)
    #pragma unroll
    for (int nt = 0; nt < 4; nt++) {
      bs[kc][nt] = *(const short8*)(wfS + ((kc * 4 + nt) * 64 + lane) * 8);
      bn[kc][nt] = *(const short8*)(wfN + ((kc * 4 + nt) * 64 + lane) * 8);
    }
  float bv[4];
  #pragma unroll
  for (int nt = 0; nt < 4; nt++) bv[nt] = bias[nt * 16 + col];

  const int NT = N_NODES / 16;  // 6250
  for (int t = wid; t < NT; t += nw) {
    const int m = t * 16 + col;
    short8 as0 = *(const short8*)(selfb + m * 64 + rr * 8);
    short8 as1 = *(const short8*)(selfb + m * 64 + 32 + rr * 8);
    short8 aa0 = *(const short8*)(aggb + m * 64 + rr * 8);
    short8 aa1 = *(const short8*)(aggb + m * 64 + 32 + rr * 8);
    #pragma unroll
    for (int nt = 0; nt < 4; nt++) {
      float4v cfr = {bv[nt], bv[nt], bv[nt], bv[nt]};
      cfr = __builtin_amdgcn_mfma_f32_16x16x32_bf16(as0, bs[0][nt], cfr, 0, 0, 0);
      cfr = __builtin_amdgcn_mfma_f32_16x16x32_bf16(as1, bs[1][nt], cfr, 0, 0, 0);
      cfr = __builtin_amdgcn_mfma_f32_16x16x32_bf16(aa0, bn[0][nt], cfr, 0, 0, 0);
      cfr = __builtin_amdgcn_mfma_f32_16x16x32_bf16(aa1, bn[1][nt], cfr, 0, 0, 0);
      #pragma unroll
      for (int r2 = 0; r2 < 4; r2++) {
        int row = t * 16 + rr * 4 + r2;
        float v = cfr[r2];
        if (RELU) v = fmaxf(v, 0.f);
        if (OUT_BF) outb[row * 64 + nt * 16 + col] = f2bf(v);
        else        outf[row * 64 + nt * 16 + col] = v;
      }
    }
  }
}

// ---- launch ----------------------------------------------------------------

extern "C" void kernel_launch(void* const* d_in, const int* in_sizes, int n_in,
                              void* d_out, int out_size, void* d_ws, size_t ws_size,
                              hipStream_t stream) {
  const float* x   = (const float*)d_in[0];
  const int*   src = (const int*)d_in[1];
  const int*   dst = (const int*)d_in[2];
  const float* Ws1 = (const float*)d_in[3];
  const float* Wn1 = (const float*)d_in[4];
  const float* b1  = (const float*)d_in[5];
  const float* Ws2 = (const float*)d_in[6];
  const float* Wn2 = (const float*)d_in[7];
  const float* b2  = (const float*)d_in[8];

  char* ws = (char*)d_ws;
  int*            off  = (int*)(ws + 0);                    // N+1 ints
  int*            cur  = (int*)(ws + 400384);               // N ints
  int*            esrc = (int*)(ws + 800768);               // E ints, ends 7200768
  unsigned short* wf   = (unsigned short*)(ws + 7200768);   // 32 KB frag weights
  unsigned short* xbf  = (unsigned short*)(ws + 7233536);   // N*64 bf16
  unsigned short* hbf  = (unsigned short*)(ws + 20033536);  // N*64 bf16, ends 32833536
  int*            binned = (int*)(ws + 20033536);           // E ints, aliases hbf (consumed first)

  // scratch in upper half of d_out (free until final k_xform writes it)
  char* dox = (char*)d_out;
  int* blkCnt   = (int*)(dox + 13000000);  // NBKT*256 ints = 200704 B
  int* bktTot   = (int*)(dox + 13300000);  // NBKT ints
  int* bktStart = (int*)(dox + 13400000);  // NBKT ints

  unsigned short* agg1 = (unsigned short*)d_out;  // first 12.8 MB of d_out
  unsigned short* agg2 = xbf;                     // reuse after layer-1 transform

  kA_count<<<256, 256, 0, stream>>>(dst, blkCnt);
  kA_scan1<<<NBKT, 256, 0, stream>>>(blkCnt, bktTot);
  kA_scan2<<<1, 64, 0, stream>>>(bktTot, bktStart);
  kA_scatter<<<256, 256, 0, stream>>>(src, dst, blkCnt, bktStart, binned);
  k_degoff<<<NBKT, 256, 0, stream>>>(binned, bktStart, bktTot, off, cur);
  kB_scatter<<<NBKT, 256, 0, stream>>>(binned, bktStart, bktTot, cur, esrc);

  k_cvt<<<(N_NODES * 16 + 255) / 256, 256, 0, stream>>>(x, xbf);
  k_wprep<<<4, 64, 0, stream>>>(Ws1, Wn1, Ws2, Wn2, wf);

  k_agg<<<2048, 256, 0, stream>>>(xbf, off, esrc, agg1);
  k_xform<true, true><<<1024, 256, 0, stream>>>(xbf, agg1, wf + 0 * 4096, wf + 1 * 4096,
                                                b1, nullptr, hbf);
  k_agg<<<2048, 256, 0, stream>>>(hbf, off, esrc, agg2);
  k_xform<false, false><<<1024, 256, 0, stream>>>(hbf, agg2, wf + 2 * 4096, wf + 3 * 4096,
                                                  b2, (float*)d_out, nullptr);
}